// Round 2
// baseline (3139.070 us; speedup 1.0000x reference)
//
#include <hip/hip_runtime.h>
#include <hip/hip_bf16.h>

// Problem constants (GraphNet): N=50000 nodes, F=128 feats, H=128, MH=256, E=800000 edges
// Inputs are FP32 (reference dtypes); we cast to bf16 in workspace for MFMA.
#define NN 50000
#define F 128
#define EE 800000
#define MHD 256

typedef __attribute__((ext_vector_type(8))) short bf16x8;   // 8 bf16 in 4 VGPRs
typedef __attribute__((ext_vector_type(4))) float f32x4;

__device__ __forceinline__ float b2f(unsigned short u) {
    union { unsigned int i; float f; } v; v.i = ((unsigned)u) << 16; return v.f;
}
__device__ __forceinline__ unsigned short f2b(float f) {
    unsigned int x = __float_as_uint(f);
    unsigned int r = x + 0x7fffu + ((x >> 16) & 1u);   // RNE
    return (unsigned short)(r >> 16);
}

// ---------------- fp32 -> bf16 cast of x [N*F elements] ----------------
__global__ __launch_bounds__(256) void cast_x_kernel(
    const float* __restrict__ in, unsigned short* __restrict__ out) {
    int i = (blockIdx.x * 256 + threadIdx.x) * 4;        // 6.4M elements / 4
    float4 v = *(const float4*)(in + i);
    ushort4 o; o.x = f2b(v.x); o.y = f2b(v.y); o.z = f2b(v.z); o.w = f2b(v.w);
    *(ushort4*)(out + i) = o;
}

// ---------------- fp32 -> bf16 cast of the 5 weight matrices ----------------
// wb layout (elements): W1l@0, W1r@16384, W2l@32768, W2r@49152, Wm1@65536 (65536)
__global__ __launch_bounds__(256) void cast_w_kernel(
    const float* __restrict__ W1l, const float* __restrict__ W1r,
    const float* __restrict__ W2l, const float* __restrict__ W2r,
    const float* __restrict__ Wm1, unsigned short* __restrict__ wb) {
    int i = (blockIdx.x * 256 + threadIdx.x) * 4;        // 131072 elements / 4
    const float* p;
    if (i < 16384)      p = W1l + i;
    else if (i < 32768) p = W1r + (i - 16384);
    else if (i < 49152) p = W2l + (i - 32768);
    else if (i < 65536) p = W2r + (i - 49152);
    else                p = Wm1 + (i - 65536);
    float4 v = *(const float4*)p;
    ushort4 o; o.x = f2b(v.x); o.y = f2b(v.y); o.z = f2b(v.z); o.w = f2b(v.w);
    *(ushort4*)(wb + i) = o;
}

// ---------------- edge_index canonicalize -> int32 src/dst ----------------
// Handles both int32 [2,E] and int64 [2,E] delivery. int64 detected iff all odd
// 32-bit words of the first 64 pairs are zero (values < 2^31 so high words are 0).
__global__ __launch_bounds__(256) void edge_cvt_kernel(
    const int* __restrict__ ei, int* __restrict__ s32, int* __restrict__ d32) {
    __shared__ int isI64;
    if (threadIdx.x == 0) {
        int z = 0;
        for (int i = 1; i < 128; i += 2) z |= ei[i];
        isI64 = (z == 0) ? 1 : 0;
    }
    __syncthreads();
    int e = blockIdx.x * 256 + threadIdx.x;
    if (e >= EE) return;
    if (isI64) {
        const long long* e64 = (const long long*)ei;
        s32[e] = (int)e64[e];
        d32[e] = (int)e64[EE + e];
    } else {
        s32[e] = ei[e];
        d32[e] = ei[EE + e];
    }
}

// ---------------- scatter-add aggregation: agg[dst] += x[src], cnt[dst] += 1 ----------------
// 32 threads per edge, 4 feats each (8B bf16x4 load, 4 fp32 atomics)
__global__ __launch_bounds__(256) void scatter_kernel(
    const unsigned short* __restrict__ xin,
    const int* __restrict__ src, const int* __restrict__ dst,
    float* __restrict__ agg, float* __restrict__ cnt, int addCnt) {
    int gtid = blockIdx.x * 256 + threadIdx.x;      // E*32 = 25.6M threads
    int e = gtid >> 5;
    if (e >= EE) return;
    int g = gtid & 31;
    int s = src[e], d = dst[e];
    ushort4 v = *(const ushort4*)(xin + (size_t)s * F + g * 4);
    float* ap = agg + (size_t)d * F + g * 4;
    atomicAdd(ap + 0, b2f(v.x));
    atomicAdd(ap + 1, b2f(v.y));
    atomicAdd(ap + 2, b2f(v.z));
    atomicAdd(ap + 3, b2f(v.w));
    if (addCnt && g == 0) atomicAdd(cnt + d, 1.0f);
}

// ---------------- mean + fp32->bf16 ----------------
__global__ __launch_bounds__(256) void mean_kernel(
    const float* __restrict__ agg, const float* __restrict__ cnt,
    unsigned short* __restrict__ aggb) {
    int t = blockIdx.x * 256 + threadIdx.x;         // N*32 threads
    int node = t >> 5, g = t & 31;
    if (node >= NN) return;
    float inv = 1.0f / fmaxf(cnt[node], 1.0f);
    float4 v = *(const float4*)(agg + (size_t)node * F + g * 4);
    ushort4 o;
    o.x = f2b(v.x * inv); o.y = f2b(v.y * inv);
    o.z = f2b(v.z * inv); o.w = f2b(v.w * inv);
    *(ushort4*)(aggb + (size_t)node * F + g * 4) = o;
}

// ---------------- fused SAGE combine: out = relu(A1@W1^T + bias + A2@W2^T) ----------------
// A1,A2:[N,128] bf16; W1,W2:[128,128] bf16 row-major; bias fp32. 4 waves/block, 16 nodes/wave.
// MFMA 16x16x32: A[m=lane&15][k=q*8+j]; B[k][n]=W[n][k] contiguous from W row n=nt*16+(lane&15).
// C/D: col=lane&15, row=(lane>>4)*4+reg (m89/m91-verified).
__global__ __launch_bounds__(256) void node_gemm_kernel(
    const unsigned short* __restrict__ A1, const unsigned short* __restrict__ A2,
    const unsigned short* __restrict__ W1, const unsigned short* __restrict__ W2,
    const float* __restrict__ bias,
    unsigned short* __restrict__ out) {
    int wave = threadIdx.x >> 6, lane = threadIdx.x & 63;
    int c = lane & 15, q = lane >> 4;
    int m0 = (blockIdx.x * 4 + wave) * 16;
    if (m0 >= NN) return;                 // wave-uniform, no syncthreads in kernel
    f32x4 acc[8];
    for (int nt = 0; nt < 8; nt++) {
        float b = bias[nt * 16 + c];
        acc[nt] = (f32x4){b, b, b, b};
    }
    int mrow = m0 + c; if (mrow > NN - 1) mrow = NN - 1;   // clamp loads, guard stores
    for (int op = 0; op < 2; op++) {
        const unsigned short* ap = (op ? A2 : A1) + (size_t)mrow * F + q * 8;
        const unsigned short* W  = op ? W2 : W1;
        for (int kb = 0; kb < 4; kb++) {
            bf16x8 a = *(const bf16x8*)(ap + kb * 32);
            for (int nt = 0; nt < 8; nt++) {
                bf16x8 b = *(const bf16x8*)(W + (size_t)(nt * 16 + c) * F + kb * 32 + q * 8);
                acc[nt] = __builtin_amdgcn_mfma_f32_16x16x32_bf16(a, b, acc[nt], 0, 0, 0);
            }
        }
    }
    for (int nt = 0; nt < 8; nt++) {
        for (int r = 0; r < 4; r++) {
            int node = m0 + q * 4 + r;
            if (node < NN) {
                float v = fmaxf(acc[nt][r], 0.0f);
                out[(size_t)node * F + nt * 16 + c] = f2b(v);
            }
        }
    }
}

// ---------------- edge MLP: out[e] = relu(concat(h[src],h[dst]) @ Wm1^T + bm1) . Wm2 + bm2 ----
// 256 edges/block, 4 waves x 4 mtiles of 16 edges. Wm1 (bf16) staged in 64-row quarters into
// LDS in MFMA fragment order -> conflict-free ds_read_b128 at lane*16. Output fp32.
__global__ __launch_bounds__(256) void edge_mlp_kernel(
    const unsigned short* __restrict__ h,
    const int* __restrict__ src, const int* __restrict__ dst,
    const unsigned short* __restrict__ Wm1, const float* __restrict__ bm1,
    const float* __restrict__ Wm2, const float* __restrict__ bm2,
    float* __restrict__ out) {
    __shared__ unsigned short wlds[32 * 512];   // 32 frag-blocks x 1KB = 32 KB
    int t = threadIdx.x;
    int wave = t >> 6, lane = t & 63, c = lane & 15, q = lane >> 4;
    int eBase = blockIdx.x * 256 + wave * 64;
    f32x4 po[4];
    for (int mt = 0; mt < 4; mt++) po[mt] = (f32x4){0.f, 0.f, 0.f, 0.f};

    for (int s = 0; s < 4; s++) {               // 64-output-row quarters of Wm1
        __syncthreads();
        // stage quarter s in fragment order: block (nt,kb) holds lanes' 16B frags contiguously
        for (int i = 0; i < 8; i++) {
            int sid = i * 256 + t;
            int blk = sid >> 6;                 // 0..31 = nt*8+kb
            int l = sid & 63;
            int row = s * 64 + (blk >> 3) * 16 + (l & 15);
            int k = (blk & 7) * 32 + (l >> 4) * 8;
            *(bf16x8*)(wlds + blk * 512 + l * 8) =
                *(const bf16x8*)(Wm1 + (size_t)row * MHD + k);
        }
        __syncthreads();
        for (int mt = 0; mt < 4; mt++) {
            int e = eBase + mt * 16 + c;        // A-frag row m = lane&15
            int sn = src[e], dn = dst[e];
            bf16x8 af[8];
            for (int kb = 0; kb < 8; kb++) {
                int k0 = kb * 32 + q * 8;       // 0..248
                int node = (k0 < 128) ? sn : dn;
                af[kb] = *(const bf16x8*)(h + (size_t)node * F + (k0 & 127));
            }
            f32x4 acc[4];
            for (int nt = 0; nt < 4; nt++) {
                float b = bm1[s * 64 + nt * 16 + c];
                acc[nt] = (f32x4){b, b, b, b};
            }
            for (int kb = 0; kb < 8; kb++) {
                for (int nt = 0; nt < 4; nt++) {
                    bf16x8 b = *(const bf16x8*)(wlds + (nt * 8 + kb) * 512 + lane * 8);
                    acc[nt] = __builtin_amdgcn_mfma_f32_16x16x32_bf16(af[kb], b, acc[nt], 0, 0, 0);
                }
            }
            for (int nt = 0; nt < 4; nt++) {
                float w2 = Wm2[s * 64 + nt * 16 + c];
                for (int r = 0; r < 4; r++)
                    po[mt][r] += fmaxf(acc[nt][r], 0.0f) * w2;
            }
        }
    }
    // reduce across the 16 cols (lanes differing in bits 0..3); row = q*4+r
    float b2 = bm2[0];
    for (int mt = 0; mt < 4; mt++) {
        for (int r = 0; r < 4; r++) {
            float v = po[mt][r];
            v += __shfl_xor(v, 1);
            v += __shfl_xor(v, 2);
            v += __shfl_xor(v, 4);
            v += __shfl_xor(v, 8);
            if (c == 0) out[eBase + mt * 16 + q * 4 + r] = v + b2;
        }
    }
}

extern "C" void kernel_launch(void* const* d_in, const int* in_sizes, int n_in,
                              void* d_out, int out_size, void* d_ws, size_t ws_size,
                              hipStream_t stream) {
    const float* x   = (const float*)d_in[0];
    const int*   ei  = (const int*)d_in[1];
    const float* W1l = (const float*)d_in[2];
    const float* b1l = (const float*)d_in[3];
    const float* W1r = (const float*)d_in[4];
    const float* W2l = (const float*)d_in[5];
    const float* b2l = (const float*)d_in[6];
    const float* W2r = (const float*)d_in[7];
    const float* Wm1 = (const float*)d_in[8];
    const float* bm1 = (const float*)d_in[9];
    const float* Wm2 = (const float*)d_in[10];
    const float* bm2 = (const float*)d_in[11];

    // workspace layout (bytes):
    // agg f32 25.6MB | cnt 0.2MB | aggb bf16 12.8MB | xb 12.8MB | h1 12.8MB | h2 12.8MB
    // | wb bf16 0.26MB | s32 3.2MB | d32 3.2MB   (total ~83.7MB)
    char* ws = (char*)d_ws;
    float*          agg  = (float*)ws;
    float*          cnt  = (float*)(ws + 25600000);
    unsigned short* aggb = (unsigned short*)(ws + 25800000);
    unsigned short* xb   = (unsigned short*)(ws + 38600000);
    unsigned short* h1   = (unsigned short*)(ws + 51400000);
    unsigned short* h2   = (unsigned short*)(ws + 64200000);
    unsigned short* wb   = (unsigned short*)(ws + 77000000);
    int*            s32  = (int*)(ws + 77262144);
    int*            d32  = (int*)(ws + 80462144);
    float*          outp = (float*)d_out;

    const unsigned short* w1l_b = wb;
    const unsigned short* w1r_b = wb + 16384;
    const unsigned short* w2l_b = wb + 32768;
    const unsigned short* w2r_b = wb + 49152;
    const unsigned short* wm1_b = wb + 65536;

    // prep: casts + index canonicalization
    cast_x_kernel<<<6250, 256, 0, stream>>>(x, xb);          // 6.4M elems
    cast_w_kernel<<<128, 256, 0, stream>>>(W1l, W1r, W2l, W2r, Wm1, wb);
    edge_cvt_kernel<<<3125, 256, 0, stream>>>(ei, s32, d32);

    // layer 1
    hipMemsetAsync(agg, 0, 25800000, stream);                // agg + cnt
    scatter_kernel<<<100000, 256, 0, stream>>>(xb, s32, d32, agg, cnt, 1);
    mean_kernel<<<6250, 256, 0, stream>>>(agg, cnt, aggb);
    node_gemm_kernel<<<782, 256, 0, stream>>>(aggb, xb, w1l_b, w1r_b, b1l, h1);
    // layer 2 (counts unchanged)
    hipMemsetAsync(agg, 0, 25600000, stream);
    scatter_kernel<<<100000, 256, 0, stream>>>(h1, s32, d32, agg, cnt, 0);
    mean_kernel<<<6250, 256, 0, stream>>>(agg, cnt, aggb);
    node_gemm_kernel<<<782, 256, 0, stream>>>(aggb, h1, w2l_b, w2r_b, b2l, h2);
    // edge MLP
    edge_mlp_kernel<<<3125, 256, 0, stream>>>(h2, s32, d32, wm1_b, bm1, Wm2, bm2, outp);
}

// Round 3
// 685.502 us; speedup vs baseline: 4.5792x; 4.5792x over previous
//
#include <hip/hip_runtime.h>
#include <hip/hip_bf16.h>

// GraphNet: N=50000 nodes, F=128 feats, H=128, MH=256, E=800000 edges
// Inputs FP32; bf16 workspace copies for MFMA; fp32 MFMA accumulation.
#define NN 50000
#define F 128
#define EE 800000
#define MHD 256

typedef __attribute__((ext_vector_type(8))) short bf16x8;
typedef __attribute__((ext_vector_type(4))) float f32x4;

__device__ __forceinline__ float b2f(unsigned short u) {
    union { unsigned int i; float f; } v; v.i = ((unsigned)u) << 16; return v.f;
}
__device__ __forceinline__ unsigned short f2b(float f) {
    unsigned int x = __float_as_uint(f);
    unsigned int r = x + 0x7fffu + ((x >> 16) & 1u);   // RNE
    return (unsigned short)(r >> 16);
}

// ---------------- fp32 -> bf16 cast of x ----------------
__global__ __launch_bounds__(256) void cast_x_kernel(
    const float* __restrict__ in, unsigned short* __restrict__ out) {
    int i = (blockIdx.x * 256 + threadIdx.x) * 4;
    float4 v = *(const float4*)(in + i);
    ushort4 o; o.x = f2b(v.x); o.y = f2b(v.y); o.z = f2b(v.z); o.w = f2b(v.w);
    *(ushort4*)(out + i) = o;
}

// ---------------- fp32 -> bf16 cast of the 5 weight matrices ----------------
// wb layout (elements): W1l@0, W1r@16384, W2l@32768, W2r@49152, Wm1@65536 (65536)
__global__ __launch_bounds__(256) void cast_w_kernel(
    const float* __restrict__ W1l, const float* __restrict__ W1r,
    const float* __restrict__ W2l, const float* __restrict__ W2r,
    const float* __restrict__ Wm1, unsigned short* __restrict__ wb) {
    int i = (blockIdx.x * 256 + threadIdx.x) * 4;
    const float* p;
    if (i < 16384)      p = W1l + i;
    else if (i < 32768) p = W1r + (i - 16384);
    else if (i < 49152) p = W2l + (i - 32768);
    else if (i < 65536) p = W2r + (i - 49152);
    else                p = Wm1 + (i - 65536);
    float4 v = *(const float4*)p;
    ushort4 o; o.x = f2b(v.x); o.y = f2b(v.y); o.z = f2b(v.z); o.w = f2b(v.w);
    *(ushort4*)(wb + i) = o;
}

// ---------------- edge_index canonicalize -> int32 src/dst ----------------
__global__ __launch_bounds__(256) void edge_cvt_kernel(
    const int* __restrict__ ei, int* __restrict__ s32, int* __restrict__ d32) {
    __shared__ int isI64;
    if (threadIdx.x == 0) {
        int z = 0;
        for (int i = 1; i < 128; i += 2) z |= ei[i];
        isI64 = (z == 0) ? 1 : 0;
    }
    __syncthreads();
    int e = blockIdx.x * 256 + threadIdx.x;
    if (e >= EE) return;
    if (isI64) {
        const long long* e64 = (const long long*)ei;
        s32[e] = (int)e64[e];
        d32[e] = (int)e64[EE + e];
    } else {
        s32[e] = ei[e];
        d32[e] = ei[EE + e];
    }
}

// ---------------- CSR build: histogram -> scan -> fill ----------------
__global__ __launch_bounds__(256) void hist_kernel(
    const int* __restrict__ d32, int* __restrict__ deg) {
    int e = blockIdx.x * 256 + threadIdx.x;
    if (e < EE) atomicAdd(&deg[d32[e]], 1);
}

#define SCAN_T 1024
#define SCHUNK 49   // 1024*49 = 50176 >= NN
__global__ __launch_bounds__(1024) void scan_kernel(
    const int* __restrict__ deg, int* __restrict__ rowstart, int* __restrict__ cursor) {
    __shared__ int part[SCAN_T];
    int t = threadIdx.x;
    int beg = t * SCHUNK, end = min(beg + SCHUNK, NN);
    int s = 0;
    for (int i = beg; i < end; i++) s += deg[i];
    part[t] = s;
    __syncthreads();
    for (int off = 1; off < SCAN_T; off <<= 1) {     // Hillis-Steele inclusive
        int v = (t >= off) ? part[t - off] : 0;
        __syncthreads();
        part[t] += v;
        __syncthreads();
    }
    int run = (t == 0) ? 0 : part[t - 1];
    for (int i = beg; i < end; i++) {
        rowstart[i] = run; cursor[i] = run; run += deg[i];
    }
    if (t == SCAN_T - 1) rowstart[NN] = run;         // = E
}

__global__ __launch_bounds__(256) void fill_kernel(
    const int* __restrict__ s32, const int* __restrict__ d32,
    int* __restrict__ cursor, int* __restrict__ nbr) {
    int e = blockIdx.x * 256 + threadIdx.x;
    if (e < EE) {
        int p = atomicAdd(&cursor[d32[e]], 1);
        nbr[p] = s32[e];
    }
}

// ---------------- gather aggregation + mean: aggb[n] = mean_{s in nbr(n)} x[s] ----------------
// One wave per node; lane handles 2 feats (ushort2 = 256B/row coalesced gather).
__global__ __launch_bounds__(256) void agg_gather_kernel(
    const unsigned short* __restrict__ xin,
    const int* __restrict__ nbr, const int* __restrict__ rowstart,
    unsigned short* __restrict__ aggb) {
    int wave = threadIdx.x >> 6, lane = threadIdx.x & 63;
    int node = blockIdx.x * 4 + wave;
    if (node >= NN) return;
    int beg = rowstart[node], end = rowstart[node + 1];
    float a0 = 0.f, a1 = 0.f, b0 = 0.f, b1 = 0.f;
    int j = beg;
    for (; j + 1 < end; j += 2) {                    // 2-way unroll for ILP
        int s0 = nbr[j], s1 = nbr[j + 1];
        ushort2 v0 = *(const ushort2*)(xin + (size_t)s0 * F + lane * 2);
        ushort2 v1 = *(const ushort2*)(xin + (size_t)s1 * F + lane * 2);
        a0 += b2f(v0.x); a1 += b2f(v0.y);
        b0 += b2f(v1.x); b1 += b2f(v1.y);
    }
    if (j < end) {
        int s0 = nbr[j];
        ushort2 v0 = *(const ushort2*)(xin + (size_t)s0 * F + lane * 2);
        a0 += b2f(v0.x); a1 += b2f(v0.y);
    }
    float inv = 1.0f / fmaxf((float)(end - beg), 1.0f);
    ushort2 o; o.x = f2b((a0 + b0) * inv); o.y = f2b((a1 + b1) * inv);
    *(ushort2*)(aggb + (size_t)node * F + lane * 2) = o;
}

// ---------------- fused SAGE combine: out = relu(A1@W1^T + bias + A2@W2^T) ----------------
__global__ __launch_bounds__(256) void node_gemm_kernel(
    const unsigned short* __restrict__ A1, const unsigned short* __restrict__ A2,
    const unsigned short* __restrict__ W1, const unsigned short* __restrict__ W2,
    const float* __restrict__ bias,
    unsigned short* __restrict__ out) {
    int wave = threadIdx.x >> 6, lane = threadIdx.x & 63;
    int c = lane & 15, q = lane >> 4;
    int m0 = (blockIdx.x * 4 + wave) * 16;
    if (m0 >= NN) return;
    f32x4 acc[8];
    for (int nt = 0; nt < 8; nt++) {
        float b = bias[nt * 16 + c];
        acc[nt] = (f32x4){b, b, b, b};
    }
    int mrow = m0 + c; if (mrow > NN - 1) mrow = NN - 1;
    for (int op = 0; op < 2; op++) {
        const unsigned short* ap = (op ? A2 : A1) + (size_t)mrow * F + q * 8;
        const unsigned short* W  = op ? W2 : W1;
        for (int kb = 0; kb < 4; kb++) {
            bf16x8 a = *(const bf16x8*)(ap + kb * 32);
            for (int nt = 0; nt < 8; nt++) {
                bf16x8 b = *(const bf16x8*)(W + (size_t)(nt * 16 + c) * F + kb * 32 + q * 8);
                acc[nt] = __builtin_amdgcn_mfma_f32_16x16x32_bf16(a, b, acc[nt], 0, 0, 0);
            }
        }
    }
    for (int nt = 0; nt < 8; nt++) {
        for (int r = 0; r < 4; r++) {
            int node = m0 + q * 4 + r;
            if (node < NN) {
                float v = fmaxf(acc[nt][r], 0.0f);
                out[(size_t)node * F + nt * 16 + c] = f2b(v);
            }
        }
    }
}

// ---------------- edge MLP ----------------
__global__ __launch_bounds__(256) void edge_mlp_kernel(
    const unsigned short* __restrict__ h,
    const int* __restrict__ src, const int* __restrict__ dst,
    const unsigned short* __restrict__ Wm1, const float* __restrict__ bm1,
    const float* __restrict__ Wm2, const float* __restrict__ bm2,
    float* __restrict__ out) {
    __shared__ unsigned short wlds[32 * 512];
    int t = threadIdx.x;
    int wave = t >> 6, lane = t & 63, c = lane & 15, q = lane >> 4;
    int eBase = blockIdx.x * 256 + wave * 64;
    f32x4 po[4];
    for (int mt = 0; mt < 4; mt++) po[mt] = (f32x4){0.f, 0.f, 0.f, 0.f};

    for (int s = 0; s < 4; s++) {
        __syncthreads();
        for (int i = 0; i < 8; i++) {
            int sid = i * 256 + t;
            int blk = sid >> 6;
            int l = sid & 63;
            int row = s * 64 + (blk >> 3) * 16 + (l & 15);
            int k = (blk & 7) * 32 + (l >> 4) * 8;
            *(bf16x8*)(wlds + blk * 512 + l * 8) =
                *(const bf16x8*)(Wm1 + (size_t)row * MHD + k);
        }
        __syncthreads();
        for (int mt = 0; mt < 4; mt++) {
            int e = eBase + mt * 16 + c;
            int sn = src[e], dn = dst[e];
            bf16x8 af[8];
            for (int kb = 0; kb < 8; kb++) {
                int k0 = kb * 32 + q * 8;
                int node = (k0 < 128) ? sn : dn;
                af[kb] = *(const bf16x8*)(h + (size_t)node * F + (k0 & 127));
            }
            f32x4 acc[4];
            for (int nt = 0; nt < 4; nt++) {
                float b = bm1[s * 64 + nt * 16 + c];
                acc[nt] = (f32x4){b, b, b, b};
            }
            for (int kb = 0; kb < 8; kb++) {
                for (int nt = 0; nt < 4; nt++) {
                    bf16x8 b = *(const bf16x8*)(wlds + (nt * 8 + kb) * 512 + lane * 8);
                    acc[nt] = __builtin_amdgcn_mfma_f32_16x16x32_bf16(af[kb], b, acc[nt], 0, 0, 0);
                }
            }
            for (int nt = 0; nt < 4; nt++) {
                float w2 = Wm2[s * 64 + nt * 16 + c];
                for (int r = 0; r < 4; r++)
                    po[mt][r] += fmaxf(acc[nt][r], 0.0f) * w2;
            }
        }
    }
    float b2 = bm2[0];
    for (int mt = 0; mt < 4; mt++) {
        for (int r = 0; r < 4; r++) {
            float v = po[mt][r];
            v += __shfl_xor(v, 1);
            v += __shfl_xor(v, 2);
            v += __shfl_xor(v, 4);
            v += __shfl_xor(v, 8);
            if (c == 0) out[eBase + mt * 16 + q * 4 + r] = v + b2;
        }
    }
}

extern "C" void kernel_launch(void* const* d_in, const int* in_sizes, int n_in,
                              void* d_out, int out_size, void* d_ws, size_t ws_size,
                              hipStream_t stream) {
    const float* x   = (const float*)d_in[0];
    const int*   ei  = (const int*)d_in[1];
    const float* W1l = (const float*)d_in[2];
    const float* b1l = (const float*)d_in[3];
    const float* W1r = (const float*)d_in[4];
    const float* W2l = (const float*)d_in[5];
    const float* b2l = (const float*)d_in[6];
    const float* W2r = (const float*)d_in[7];
    const float* Wm1 = (const float*)d_in[8];
    const float* bm1 = (const float*)d_in[9];
    const float* Wm2 = (const float*)d_in[10];
    const float* bm2 = (const float*)d_in[11];

    // workspace (bytes): xb 12.8M | h1 12.8M | h2 12.8M | aggb 12.8M | wb 0.26M
    //                  | s32 3.2M | d32 3.2M | deg 0.2M | rowstart 0.2M | cursor 0.2M | nbr 3.2M
    char* ws = (char*)d_ws;
    unsigned short* xb       = (unsigned short*)(ws);
    unsigned short* h1       = (unsigned short*)(ws + 12800000);
    unsigned short* h2       = (unsigned short*)(ws + 25600000);
    unsigned short* aggb     = (unsigned short*)(ws + 38400000);
    unsigned short* wb       = (unsigned short*)(ws + 51200000);
    int*            s32      = (int*)(ws + 51462144);
    int*            d32      = (int*)(ws + 54662144);
    int*            deg      = (int*)(ws + 57862144);
    int*            rowstart = (int*)(ws + 58062208);
    int*            cursor   = (int*)(ws + 58262272);
    int*            nbr      = (int*)(ws + 58462336);
    float*          outp     = (float*)d_out;

    const unsigned short* w1l_b = wb;
    const unsigned short* w1r_b = wb + 16384;
    const unsigned short* w2l_b = wb + 32768;
    const unsigned short* w2r_b = wb + 49152;
    const unsigned short* wm1_b = wb + 65536;

    // prep: casts + indices + CSR build (reused by both layers)
    cast_x_kernel<<<6250, 256, 0, stream>>>(x, xb);
    cast_w_kernel<<<128, 256, 0, stream>>>(W1l, W1r, W2l, W2r, Wm1, wb);
    edge_cvt_kernel<<<3125, 256, 0, stream>>>(ei, s32, d32);
    hipMemsetAsync(deg, 0, 200064, stream);
    hist_kernel<<<3125, 256, 0, stream>>>(d32, deg);
    scan_kernel<<<1, 1024, 0, stream>>>(deg, rowstart, cursor);
    fill_kernel<<<3125, 256, 0, stream>>>(s32, d32, cursor, nbr);

    // layer 1
    agg_gather_kernel<<<12500, 256, 0, stream>>>(xb, nbr, rowstart, aggb);
    node_gemm_kernel<<<782, 256, 0, stream>>>(aggb, xb, w1l_b, w1r_b, b1l, h1);
    // layer 2
    agg_gather_kernel<<<12500, 256, 0, stream>>>(h1, nbr, rowstart, aggb);
    node_gemm_kernel<<<782, 256, 0, stream>>>(aggb, h1, w2l_b, w2r_b, b2l, h2);
    // edge MLP
    edge_mlp_kernel<<<3125, 256, 0, stream>>>(h2, s32, d32, wm1_b, bm1, Wm2, bm2, outp);
}

// Round 4
// 670.081 us; speedup vs baseline: 4.6846x; 1.0230x over previous
//
#include <hip/hip_runtime.h>
#include <hip/hip_bf16.h>

// GraphNet: N=50000 nodes, F=128 feats, H=128, MH=256, E=800000 edges
// Inputs FP32; bf16 workspace copies for MFMA; fp32 MFMA accumulation.
#define NN 50000
#define F 128
#define EE 800000
#define MHD 256

typedef __attribute__((ext_vector_type(8))) short bf16x8;
typedef __attribute__((ext_vector_type(4))) float f32x4;
typedef __attribute__((ext_vector_type(16))) float f32x16;

__device__ __forceinline__ float b2f(unsigned short u) {
    union { unsigned int i; float f; } v; v.i = ((unsigned)u) << 16; return v.f;
}
__device__ __forceinline__ unsigned short f2b(float f) {
    unsigned int x = __float_as_uint(f);
    unsigned int r = x + 0x7fffu + ((x >> 16) & 1u);   // RNE
    return (unsigned short)(r >> 16);
}

// ---------------- fp32 -> bf16 cast of x ----------------
__global__ __launch_bounds__(256) void cast_x_kernel(
    const float* __restrict__ in, unsigned short* __restrict__ out) {
    int i = (blockIdx.x * 256 + threadIdx.x) * 4;
    float4 v = *(const float4*)(in + i);
    ushort4 o; o.x = f2b(v.x); o.y = f2b(v.y); o.z = f2b(v.z); o.w = f2b(v.w);
    *(ushort4*)(out + i) = o;
}

// ---------------- fp32 -> bf16 cast of the 4 node-layer weights ----------------
// wb layout (elements): W1l@0, W1r@16384, W2l@32768, W2r@49152
__global__ __launch_bounds__(256) void cast_w_kernel(
    const float* __restrict__ W1l, const float* __restrict__ W1r,
    const float* __restrict__ W2l, const float* __restrict__ W2r,
    unsigned short* __restrict__ wb) {
    int i = (blockIdx.x * 256 + threadIdx.x) * 4;        // 65536 elems / 4
    const float* p;
    if (i < 16384)      p = W1l + i;
    else if (i < 32768) p = W1r + (i - 16384);
    else if (i < 49152) p = W2l + (i - 32768);
    else                p = W2r + (i - 49152);
    float4 v = *(const float4*)p;
    ushort4 o; o.x = f2b(v.x); o.y = f2b(v.y); o.z = f2b(v.z); o.w = f2b(v.w);
    *(ushort4*)(wb + i) = o;
}

// ---------------- Wm1 fp32 -> bf16, reordered into 32x32x16 B-fragment order ----------------
// frag-block q = (s*2+nt2)*16 + ks (0..127); lane l holds Wm1[sn*32+(l&31)][ks*16+(l>>5)*8 ..+8]
__global__ __launch_bounds__(256) void frag_wm1_kernel(
    const float* __restrict__ Wm1, unsigned short* __restrict__ wm1f) {
    int gid = blockIdx.x * 256 + threadIdx.x;            // 8192 threads
    int l = gid & 63;
    int q = gid >> 6;                                    // 0..127
    int ks = q & 15, sn = q >> 4;                        // sn = s*2+nt2
    int row = sn * 32 + (l & 31);
    int col = ks * 16 + (l >> 5) * 8;
    const float* p = Wm1 + row * MHD + col;
    float4 v0 = *(const float4*)p;
    float4 v1 = *(const float4*)(p + 4);
    unsigned short o[8];
    o[0]=f2b(v0.x); o[1]=f2b(v0.y); o[2]=f2b(v0.z); o[3]=f2b(v0.w);
    o[4]=f2b(v1.x); o[5]=f2b(v1.y); o[6]=f2b(v1.z); o[7]=f2b(v1.w);
    *(bf16x8*)(wm1f + (size_t)gid * 8) = *(bf16x8*)o;
}

// ---------------- edge_index canonicalize -> int32 src/dst ----------------
__global__ __launch_bounds__(256) void edge_cvt_kernel(
    const int* __restrict__ ei, int* __restrict__ s32, int* __restrict__ d32) {
    __shared__ int isI64;
    if (threadIdx.x == 0) {
        int z = 0;
        for (int i = 1; i < 128; i += 2) z |= ei[i];
        isI64 = (z == 0) ? 1 : 0;
    }
    __syncthreads();
    int e = blockIdx.x * 256 + threadIdx.x;
    if (e >= EE) return;
    if (isI64) {
        const long long* e64 = (const long long*)ei;
        s32[e] = (int)e64[e];
        d32[e] = (int)e64[EE + e];
    } else {
        s32[e] = ei[e];
        d32[e] = ei[EE + e];
    }
}

// ---------------- CSR build: histogram -> scan -> fill ----------------
__global__ __launch_bounds__(256) void hist_kernel(
    const int* __restrict__ d32, int* __restrict__ deg) {
    int e = blockIdx.x * 256 + threadIdx.x;
    if (e < EE) atomicAdd(&deg[d32[e]], 1);
}

#define SCAN_T 1024
#define SCHUNK 49   // 1024*49 = 50176 >= NN
__global__ __launch_bounds__(1024) void scan_kernel(
    const int* __restrict__ deg, int* __restrict__ rowstart, int* __restrict__ cursor) {
    __shared__ int part[SCAN_T];
    int t = threadIdx.x;
    int beg = t * SCHUNK, end = min(beg + SCHUNK, NN);
    int s = 0;
    for (int i = beg; i < end; i++) s += deg[i];
    part[t] = s;
    __syncthreads();
    for (int off = 1; off < SCAN_T; off <<= 1) {
        int v = (t >= off) ? part[t - off] : 0;
        __syncthreads();
        part[t] += v;
        __syncthreads();
    }
    int run = (t == 0) ? 0 : part[t - 1];
    for (int i = beg; i < end; i++) {
        rowstart[i] = run; cursor[i] = run; run += deg[i];
    }
    if (t == SCAN_T - 1) rowstart[NN] = run;
}

__global__ __launch_bounds__(256) void fill_kernel(
    const int* __restrict__ s32, const int* __restrict__ d32,
    int* __restrict__ cursor, int* __restrict__ nbr) {
    int e = blockIdx.x * 256 + threadIdx.x;
    if (e < EE) {
        int p = atomicAdd(&cursor[d32[e]], 1);
        nbr[p] = s32[e];
    }
}

// ---------------- gather aggregation + mean ----------------
// One wave/node; 16 lanes x 16B per neighbor row -> 4 neighbors per load instr, unroll 2.
__global__ __launch_bounds__(256) void agg_gather_kernel(
    const unsigned short* __restrict__ xin,
    const int* __restrict__ nbr, const int* __restrict__ rowstart,
    unsigned short* __restrict__ aggb) {
    int wave = threadIdx.x >> 6, lane = threadIdx.x & 63;
    int node = blockIdx.x * 4 + wave;
    if (node >= NN) return;
    int part = lane >> 4;                    // 0..3: which neighbor in group of 4
    int col8 = (lane & 15) * 8;              // 8 feats per lane
    int beg = rowstart[node], end = rowstart[node + 1];
    float a[8] = {0,0,0,0,0,0,0,0};
    float b[8] = {0,0,0,0,0,0,0,0};
    int j = beg + part;
    for (; j + 4 < end; j += 8) {            // 2 outstanding 16B loads, 8 nbrs/wave in flight
        int s0 = nbr[j], s1 = nbr[j + 4];
        bf16x8 v0 = *(const bf16x8*)(xin + (size_t)s0 * F + col8);
        bf16x8 v1 = *(const bf16x8*)(xin + (size_t)s1 * F + col8);
        for (int i = 0; i < 8; i++) a[i] += b2f((unsigned short)v0[i]);
        for (int i = 0; i < 8; i++) b[i] += b2f((unsigned short)v1[i]);
    }
    if (j < end) {
        int s0 = nbr[j];
        bf16x8 v0 = *(const bf16x8*)(xin + (size_t)s0 * F + col8);
        for (int i = 0; i < 8; i++) a[i] += b2f((unsigned short)v0[i]);
    }
    float inv = 1.0f / fmaxf((float)(end - beg), 1.0f);
    unsigned short o[8];
    for (int i = 0; i < 8; i++) {
        float v = a[i] + b[i];
        v += __shfl_xor(v, 16);
        v += __shfl_xor(v, 32);
        o[i] = f2b(v * inv);
    }
    if (part == 0)
        *(bf16x8*)(aggb + (size_t)node * F + col8) = *(bf16x8*)o;
}

// ---------------- fused SAGE combine: out = relu(A1@W1^T + bias + A2@W2^T) ----------------
__global__ __launch_bounds__(256) void node_gemm_kernel(
    const unsigned short* __restrict__ A1, const unsigned short* __restrict__ A2,
    const unsigned short* __restrict__ W1, const unsigned short* __restrict__ W2,
    const float* __restrict__ bias,
    unsigned short* __restrict__ out) {
    int wave = threadIdx.x >> 6, lane = threadIdx.x & 63;
    int c = lane & 15, q = lane >> 4;
    int m0 = (blockIdx.x * 4 + wave) * 16;
    if (m0 >= NN) return;
    f32x4 acc[8];
    for (int nt = 0; nt < 8; nt++) {
        float b = bias[nt * 16 + c];
        acc[nt] = (f32x4){b, b, b, b};
    }
    int mrow = m0 + c; if (mrow > NN - 1) mrow = NN - 1;
    for (int op = 0; op < 2; op++) {
        const unsigned short* ap = (op ? A2 : A1) + (size_t)mrow * F + q * 8;
        const unsigned short* W  = op ? W2 : W1;
        for (int kb = 0; kb < 4; kb++) {
            bf16x8 a = *(const bf16x8*)(ap + kb * 32);
            for (int nt = 0; nt < 8; nt++) {
                bf16x8 b = *(const bf16x8*)(W + (size_t)(nt * 16 + c) * F + kb * 32 + q * 8);
                acc[nt] = __builtin_amdgcn_mfma_f32_16x16x32_bf16(a, b, acc[nt], 0, 0, 0);
            }
        }
    }
    for (int nt = 0; nt < 8; nt++) {
        for (int r = 0; r < 4; r++) {
            int node = m0 + q * 4 + r;
            if (node < NN) {
                float v = fmaxf(acc[nt][r], 0.0f);
                out[(size_t)node * F + nt * 16 + c] = f2b(v);
            }
        }
    }
}

// ---------------- edge MLP, 32x32x16 MFMA ----------------
// 32 edges/wave, 128/block. af[16] (K=256) gathered ONCE (512B/edge). Wm1 pre-fragmented ->
// contiguous LDS staging; 1 ds_read_b128 per MFMA feeding 16384 MACs.
// A: m=lane&31, k=(lane>>5)*8+j. B: n=lane&31, k=(lane>>5)*8+j.
// C/D: col=lane&31, row=(reg&3)+8*(reg>>2)+4*(lane>>5)  (m74/m101-verified).
__global__ __launch_bounds__(256) void edge_mlp_kernel(
    const unsigned short* __restrict__ h,
    const int* __restrict__ src, const int* __restrict__ dst,
    const unsigned short* __restrict__ wm1f, const float* __restrict__ bm1,
    const float* __restrict__ Wm2, const float* __restrict__ bm2,
    float* __restrict__ out) {
    __shared__ unsigned short wlds[16384];   // 32 KB: one s-quarter, 32 frag-blocks
    int t = threadIdx.x;
    int wave = t >> 6, lane = t & 63, c = lane & 31, q5 = lane >> 5;
    int e0 = blockIdx.x * 128 + wave * 32;
    int e = e0 + c;
    int sn = src[e], dn = dst[e];

    // gather A-fragments once: ef = concat(h[src], h[dst]), k = kf*16 + q5*8
    bf16x8 af[16];
    for (int kf = 0; kf < 16; kf++) {
        int k0 = kf * 16 + q5 * 8;
        const unsigned short* base = (k0 < 128) ? (h + (size_t)sn * F) : (h + (size_t)dn * F);
        af[kf] = *(const bf16x8*)(base + (k0 & 127));
    }

    float po[16];
    for (int r = 0; r < 16; r++) po[r] = 0.f;

    for (int s = 0; s < 4; s++) {
        __syncthreads();
        // contiguous stage of 32KB quarter s
        const bf16x8* gsrc = (const bf16x8*)(wm1f + s * 16384);
        bf16x8* ldst = (bf16x8*)wlds;
        for (int i = 0; i < 8; i++) {
            int idx = i * 256 + t;
            ldst[idx] = gsrc[idx];
        }
        __syncthreads();
        for (int nt2 = 0; nt2 < 2; nt2++) {
            int o = s * 64 + nt2 * 32 + c;
            float bv = bm1[o];
            f32x16 acc;
            for (int r = 0; r < 16; r++) acc[r] = bv;
            const bf16x8* bbase = (const bf16x8*)(wlds) + nt2 * 16 * 64;
            for (int ks = 0; ks < 16; ks++) {
                bf16x8 bf = bbase[ks * 64 + lane];
                acc = __builtin_amdgcn_mfma_f32_32x32x16_bf16(af[ks], bf, acc, 0, 0, 0);
            }
            float w2 = Wm2[o];
            for (int r = 0; r < 16; r++)
                po[r] += fmaxf(acc[r], 0.0f) * w2;
        }
    }
    // reduce over the 32 output cols (lanes differing in bits 0..4)
    float b2 = bm2[0];
    for (int r = 0; r < 16; r++) {
        float v = po[r];
        v += __shfl_xor(v, 1);
        v += __shfl_xor(v, 2);
        v += __shfl_xor(v, 4);
        v += __shfl_xor(v, 8);
        v += __shfl_xor(v, 16);
        if (c == 0) {
            int row = (r & 3) + 8 * (r >> 2) + 4 * q5;
            out[e0 + row] = v + b2;
        }
    }
}

extern "C" void kernel_launch(void* const* d_in, const int* in_sizes, int n_in,
                              void* d_out, int out_size, void* d_ws, size_t ws_size,
                              hipStream_t stream) {
    const float* x   = (const float*)d_in[0];
    const int*   ei  = (const int*)d_in[1];
    const float* W1l = (const float*)d_in[2];
    const float* b1l = (const float*)d_in[3];
    const float* W1r = (const float*)d_in[4];
    const float* W2l = (const float*)d_in[5];
    const float* b2l = (const float*)d_in[6];
    const float* W2r = (const float*)d_in[7];
    const float* Wm1 = (const float*)d_in[8];
    const float* bm1 = (const float*)d_in[9];
    const float* Wm2 = (const float*)d_in[10];
    const float* bm2 = (const float*)d_in[11];

    // workspace (bytes): xb 12.8M | h1 12.8M | h2 12.8M | aggb 12.8M | wb+wm1f 0.26M
    //                  | s32 3.2M | d32 3.2M | deg 0.2M | rowstart 0.2M | cursor 0.2M | nbr 3.2M
    char* ws = (char*)d_ws;
    unsigned short* xb       = (unsigned short*)(ws);
    unsigned short* h1       = (unsigned short*)(ws + 12800000);
    unsigned short* h2       = (unsigned short*)(ws + 25600000);
    unsigned short* aggb     = (unsigned short*)(ws + 38400000);
    unsigned short* wb       = (unsigned short*)(ws + 51200000);
    int*            s32      = (int*)(ws + 51462144);
    int*            d32      = (int*)(ws + 54662144);
    int*            deg      = (int*)(ws + 57862144);
    int*            rowstart = (int*)(ws + 58062208);
    int*            cursor   = (int*)(ws + 58262272);
    int*            nbr      = (int*)(ws + 58462336);
    float*          outp     = (float*)d_out;

    const unsigned short* w1l_b = wb;
    const unsigned short* w1r_b = wb + 16384;
    const unsigned short* w2l_b = wb + 32768;
    const unsigned short* w2r_b = wb + 49152;
    unsigned short*       wm1f  = wb + 65536;        // 65536 elems, fragment-ordered

    // prep: casts + fragment reorder + indices + CSR build
    cast_x_kernel<<<6250, 256, 0, stream>>>(x, xb);
    cast_w_kernel<<<64, 256, 0, stream>>>(W1l, W1r, W2l, W2r, wb);
    frag_wm1_kernel<<<32, 256, 0, stream>>>(Wm1, wm1f);
    edge_cvt_kernel<<<3125, 256, 0, stream>>>(ei, s32, d32);
    hipMemsetAsync(deg, 0, 200064, stream);
    hist_kernel<<<3125, 256, 0, stream>>>(d32, deg);
    scan_kernel<<<1, 1024, 0, stream>>>(deg, rowstart, cursor);
    fill_kernel<<<3125, 256, 0, stream>>>(s32, d32, cursor, nbr);

    // layer 1
    agg_gather_kernel<<<12500, 256, 0, stream>>>(xb, nbr, rowstart, aggb);
    node_gemm_kernel<<<782, 256, 0, stream>>>(aggb, xb, w1l_b, w1r_b, b1l, h1);
    // layer 2
    agg_gather_kernel<<<12500, 256, 0, stream>>>(h1, nbr, rowstart, aggb);
    node_gemm_kernel<<<782, 256, 0, stream>>>(aggb, h1, w2l_b, w2r_b, b2l, h2);
    // edge MLP
    edge_mlp_kernel<<<6250, 256, 0, stream>>>(h2, s32, d32, wm1f, bm1, Wm2, bm2, outp);
}

// Round 5
// 596.057 us; speedup vs baseline: 5.2664x; 1.1242x over previous
//
#include <hip/hip_runtime.h>
#include <hip/hip_bf16.h>

// GraphNet: N=50000 nodes, F=128 feats, H=128, MH=256, E=800000 edges
// Inputs FP32; bf16 workspace copies for MFMA; fp32 MFMA accumulation.
#define NN 50000
#define F 128
#define EE 800000
#define MHD 256

typedef __attribute__((ext_vector_type(8))) short bf16x8;
typedef __attribute__((ext_vector_type(4))) float f32x4;
typedef __attribute__((ext_vector_type(16))) float f32x16;

__device__ __forceinline__ float b2f(unsigned short u) {
    union { unsigned int i; float f; } v; v.i = ((unsigned)u) << 16; return v.f;
}
__device__ __forceinline__ unsigned short f2b(float f) {
    unsigned int x = __float_as_uint(f);
    unsigned int r = x + 0x7fffu + ((x >> 16) & 1u);   // RNE
    return (unsigned short)(r >> 16);
}

// ---------------- fp32 -> bf16 cast of x ----------------
__global__ __launch_bounds__(256) void cast_x_kernel(
    const float* __restrict__ in, unsigned short* __restrict__ out) {
    int i = (blockIdx.x * 256 + threadIdx.x) * 4;
    float4 v = *(const float4*)(in + i);
    ushort4 o; o.x = f2b(v.x); o.y = f2b(v.y); o.z = f2b(v.z); o.w = f2b(v.w);
    *(ushort4*)(out + i) = o;
}

// ---------------- fp32 -> bf16 cast of the 4 node-layer weights ----------------
__global__ __launch_bounds__(256) void cast_w_kernel(
    const float* __restrict__ W1l, const float* __restrict__ W1r,
    const float* __restrict__ W2l, const float* __restrict__ W2r,
    unsigned short* __restrict__ wb) {
    int i = (blockIdx.x * 256 + threadIdx.x) * 4;        // 65536 elems / 4
    const float* p;
    if (i < 16384)      p = W1l + i;
    else if (i < 32768) p = W1r + (i - 16384);
    else if (i < 49152) p = W2l + (i - 32768);
    else                p = W2r + (i - 49152);
    float4 v = *(const float4*)p;
    ushort4 o; o.x = f2b(v.x); o.y = f2b(v.y); o.z = f2b(v.z); o.w = f2b(v.w);
    *(ushort4*)(wb + i) = o;
}

// ---------------- Wm1 fp32 -> bf16, reordered into 32x32x16 B-fragment order ----------------
// frag-block q = (s*2+nt2)*16 + ks (0..127); lane l holds Wm1[sn*32+(l&31)][ks*16+(l>>5)*8 ..+8]
__global__ __launch_bounds__(256) void frag_wm1_kernel(
    const float* __restrict__ Wm1, unsigned short* __restrict__ wm1f) {
    int gid = blockIdx.x * 256 + threadIdx.x;            // 8192 threads
    int l = gid & 63;
    int q = gid >> 6;                                    // 0..127
    int ks = q & 15, sn = q >> 4;                        // sn = s*2+nt2
    int row = sn * 32 + (l & 31);
    int col = ks * 16 + (l >> 5) * 8;
    const float* p = Wm1 + row * MHD + col;
    float4 v0 = *(const float4*)p;
    float4 v1 = *(const float4*)(p + 4);
    unsigned short o[8];
    o[0]=f2b(v0.x); o[1]=f2b(v0.y); o[2]=f2b(v0.z); o[3]=f2b(v0.w);
    o[4]=f2b(v1.x); o[5]=f2b(v1.y); o[6]=f2b(v1.z); o[7]=f2b(v1.w);
    *(bf16x8*)(wm1f + (size_t)gid * 8) = *(bf16x8*)o;
}

// ---------------- edge_index canonicalize -> int32 src/dst ----------------
__global__ __launch_bounds__(256) void edge_cvt_kernel(
    const int* __restrict__ ei, int* __restrict__ s32, int* __restrict__ d32) {
    __shared__ int isI64;
    if (threadIdx.x == 0) {
        int z = 0;
        for (int i = 1; i < 128; i += 2) z |= ei[i];
        isI64 = (z == 0) ? 1 : 0;
    }
    __syncthreads();
    int e = blockIdx.x * 256 + threadIdx.x;
    if (e >= EE) return;
    if (isI64) {
        const long long* e64 = (const long long*)ei;
        s32[e] = (int)e64[e];
        d32[e] = (int)e64[EE + e];
    } else {
        s32[e] = ei[e];
        d32[e] = ei[EE + e];
    }
}

// ---------------- CSR build: histogram -> scan -> fill ----------------
__global__ __launch_bounds__(256) void hist_kernel(
    const int* __restrict__ d32, int* __restrict__ deg) {
    int e = blockIdx.x * 256 + threadIdx.x;
    if (e < EE) atomicAdd(&deg[d32[e]], 1);
}

#define SCAN_T 1024
#define SCHUNK 49   // 1024*49 = 50176 >= NN
__global__ __launch_bounds__(1024) void scan_kernel(
    const int* __restrict__ deg, int* __restrict__ rowstart, int* __restrict__ cursor) {
    __shared__ int part[SCAN_T];
    int t = threadIdx.x;
    int beg = t * SCHUNK, end = min(beg + SCHUNK, NN);
    int s = 0;
    for (int i = beg; i < end; i++) s += deg[i];
    part[t] = s;
    __syncthreads();
    for (int off = 1; off < SCAN_T; off <<= 1) {
        int v = (t >= off) ? part[t - off] : 0;
        __syncthreads();
        part[t] += v;
        __syncthreads();
    }
    int run = (t == 0) ? 0 : part[t - 1];
    for (int i = beg; i < end; i++) {
        rowstart[i] = run; cursor[i] = run; run += deg[i];
    }
    if (t == SCAN_T - 1) rowstart[NN] = run;
}

__global__ __launch_bounds__(256) void fill_kernel(
    const int* __restrict__ s32, const int* __restrict__ d32,
    int* __restrict__ cursor, int* __restrict__ nbr) {
    int e = blockIdx.x * 256 + threadIdx.x;
    if (e < EE) {
        int p = atomicAdd(&cursor[d32[e]], 1);
        nbr[p] = s32[e];
    }
}

// ---------------- gather aggregation + mean ----------------
__global__ __launch_bounds__(256) void agg_gather_kernel(
    const unsigned short* __restrict__ xin,
    const int* __restrict__ nbr, const int* __restrict__ rowstart,
    unsigned short* __restrict__ aggb) {
    int wave = threadIdx.x >> 6, lane = threadIdx.x & 63;
    int node = blockIdx.x * 4 + wave;
    if (node >= NN) return;
    int part = lane >> 4;                    // 0..3: which neighbor in group of 4
    int col8 = (lane & 15) * 8;              // 8 feats per lane
    int beg = rowstart[node], end = rowstart[node + 1];
    float a[8] = {0,0,0,0,0,0,0,0};
    float b[8] = {0,0,0,0,0,0,0,0};
    int j = beg + part;
    for (; j + 4 < end; j += 8) {
        int s0 = nbr[j], s1 = nbr[j + 4];
        bf16x8 v0 = *(const bf16x8*)(xin + (size_t)s0 * F + col8);
        bf16x8 v1 = *(const bf16x8*)(xin + (size_t)s1 * F + col8);
        for (int i = 0; i < 8; i++) a[i] += b2f((unsigned short)v0[i]);
        for (int i = 0; i < 8; i++) b[i] += b2f((unsigned short)v1[i]);
    }
    if (j < end) {
        int s0 = nbr[j];
        bf16x8 v0 = *(const bf16x8*)(xin + (size_t)s0 * F + col8);
        for (int i = 0; i < 8; i++) a[i] += b2f((unsigned short)v0[i]);
    }
    float inv = 1.0f / fmaxf((float)(end - beg), 1.0f);
    unsigned short o[8];
    for (int i = 0; i < 8; i++) {
        float v = a[i] + b[i];
        v += __shfl_xor(v, 16);
        v += __shfl_xor(v, 32);
        o[i] = f2b(v * inv);
    }
    if (part == 0)
        *(bf16x8*)(aggb + (size_t)node * F + col8) = *(bf16x8*)o;
}

// ---------------- fused SAGE combine: out = relu(A1@W1^T + bias + A2@W2^T) ----------------
__global__ __launch_bounds__(256) void node_gemm_kernel(
    const unsigned short* __restrict__ A1, const unsigned short* __restrict__ A2,
    const unsigned short* __restrict__ W1, const unsigned short* __restrict__ W2,
    const float* __restrict__ bias,
    unsigned short* __restrict__ out) {
    int wave = threadIdx.x >> 6, lane = threadIdx.x & 63;
    int c = lane & 15, q = lane >> 4;
    int m0 = (blockIdx.x * 4 + wave) * 16;
    if (m0 >= NN) return;
    f32x4 acc[8];
    for (int nt = 0; nt < 8; nt++) {
        float b = bias[nt * 16 + c];
        acc[nt] = (f32x4){b, b, b, b};
    }
    int mrow = m0 + c; if (mrow > NN - 1) mrow = NN - 1;
    for (int op = 0; op < 2; op++) {
        const unsigned short* ap = (op ? A2 : A1) + (size_t)mrow * F + q * 8;
        const unsigned short* W  = op ? W2 : W1;
        for (int kb = 0; kb < 4; kb++) {
            bf16x8 a = *(const bf16x8*)(ap + kb * 32);
            for (int nt = 0; nt < 8; nt++) {
                bf16x8 b = *(const bf16x8*)(W + (size_t)(nt * 16 + c) * F + kb * 32 + q * 8);
                acc[nt] = __builtin_amdgcn_mfma_f32_16x16x32_bf16(a, b, acc[nt], 0, 0, 0);
            }
        }
    }
    for (int nt = 0; nt < 8; nt++) {
        for (int r = 0; r < 4; r++) {
            int node = m0 + q * 4 + r;
            if (node < NN) {
                float v = fmaxf(acc[nt][r], 0.0f);
                out[(size_t)node * F + nt * 16 + c] = f2b(v);
            }
        }
    }
}

// ---------------- edge MLP, 32x32x16 MFMA, 2 m-tiles per wave ----------------
// 64 edges/wave, 256/block. Each ds_read_b128 B-frag feeds TWO independent MFMA chains
// (acc0/acc1) -> LDS traffic per MFMA halved, 2 dep chains hide MFMA latency.
// A: m=lane&31, k=(lane>>5)*8+j. B: n=lane&31, k=(lane>>5)*8+j.
// C/D: col=lane&31, row=(reg&3)+8*(reg>>2)+4*(lane>>5)  (m74/m101-verified).
__global__ __launch_bounds__(256, 2) void edge_mlp_kernel(
    const unsigned short* __restrict__ h,
    const int* __restrict__ src, const int* __restrict__ dst,
    const unsigned short* __restrict__ wm1f, const float* __restrict__ bm1,
    const float* __restrict__ Wm2, const float* __restrict__ bm2,
    float* __restrict__ out) {
    __shared__ unsigned short wlds[16384];   // 32 KB: one s-quarter
    int t = threadIdx.x;
    int wave = t >> 6, lane = t & 63, c = lane & 31, q5 = lane >> 5;
    int e0 = blockIdx.x * 256 + wave * 64;   // 64 edges per wave
    int eA = e0 + c, eB = e0 + 32 + c;
    int snA = src[eA], dnA = dst[eA];
    int snB = src[eB], dnB = dst[eB];

    // gather A-fragments once per m-tile: ef = concat(h[src], h[dst]), k = kf*16 + q5*8
    bf16x8 af0[16], af1[16];
#pragma unroll
    for (int kf = 0; kf < 16; kf++) {
        int k0 = kf * 16 + q5 * 8;
        const unsigned short* baseA = (k0 < 128) ? (h + (size_t)snA * F) : (h + (size_t)dnA * F);
        const unsigned short* baseB = (k0 < 128) ? (h + (size_t)snB * F) : (h + (size_t)dnB * F);
        af0[kf] = *(const bf16x8*)(baseA + (k0 & 127));
        af1[kf] = *(const bf16x8*)(baseB + (k0 & 127));
    }

    float po0[16], po1[16];
#pragma unroll
    for (int r = 0; r < 16; r++) { po0[r] = 0.f; po1[r] = 0.f; }

    for (int s = 0; s < 4; s++) {
        __syncthreads();
        const bf16x8* gsrc = (const bf16x8*)(wm1f + s * 16384);
        bf16x8* ldst = (bf16x8*)wlds;
#pragma unroll
        for (int i = 0; i < 8; i++) {
            int idx = i * 256 + t;
            ldst[idx] = gsrc[idx];
        }
        __syncthreads();
        for (int nt2 = 0; nt2 < 2; nt2++) {
            int o = s * 64 + nt2 * 32 + c;
            float bv = bm1[o];
            f32x16 acc0, acc1;
#pragma unroll
            for (int r = 0; r < 16; r++) { acc0[r] = bv; acc1[r] = bv; }
            const bf16x8* bbase = (const bf16x8*)(wlds) + nt2 * 16 * 64;
#pragma unroll
            for (int ks = 0; ks < 16; ks++) {
                bf16x8 bf = bbase[ks * 64 + lane];
                acc0 = __builtin_amdgcn_mfma_f32_32x32x16_bf16(af0[ks], bf, acc0, 0, 0, 0);
                acc1 = __builtin_amdgcn_mfma_f32_32x32x16_bf16(af1[ks], bf, acc1, 0, 0, 0);
            }
            float w2 = Wm2[o];
#pragma unroll
            for (int r = 0; r < 16; r++) {
                po0[r] += fmaxf(acc0[r], 0.0f) * w2;
                po1[r] += fmaxf(acc1[r], 0.0f) * w2;
            }
        }
    }
    // reduce over the 32 output cols (lanes differing in bits 0..4)
    float b2 = bm2[0];
#pragma unroll
    for (int r = 0; r < 16; r++) {
        float v0 = po0[r], v1 = po1[r];
        v0 += __shfl_xor(v0, 1);  v1 += __shfl_xor(v1, 1);
        v0 += __shfl_xor(v0, 2);  v1 += __shfl_xor(v1, 2);
        v0 += __shfl_xor(v0, 4);  v1 += __shfl_xor(v1, 4);
        v0 += __shfl_xor(v0, 8);  v1 += __shfl_xor(v1, 8);
        v0 += __shfl_xor(v0, 16); v1 += __shfl_xor(v1, 16);
        if (c == 0) {
            int row = (r & 3) + 8 * (r >> 2) + 4 * q5;
            out[e0 + row] = v0 + b2;
            out[e0 + 32 + row] = v1 + b2;
        }
    }
}

extern "C" void kernel_launch(void* const* d_in, const int* in_sizes, int n_in,
                              void* d_out, int out_size, void* d_ws, size_t ws_size,
                              hipStream_t stream) {
    const float* x   = (const float*)d_in[0];
    const int*   ei  = (const int*)d_in[1];
    const float* W1l = (const float*)d_in[2];
    const float* b1l = (const float*)d_in[3];
    const float* W1r = (const float*)d_in[4];
    const float* W2l = (const float*)d_in[5];
    const float* b2l = (const float*)d_in[6];
    const float* W2r = (const float*)d_in[7];
    const float* Wm1 = (const float*)d_in[8];
    const float* bm1 = (const float*)d_in[9];
    const float* Wm2 = (const float*)d_in[10];
    const float* bm2 = (const float*)d_in[11];

    char* ws = (char*)d_ws;
    unsigned short* xb       = (unsigned short*)(ws);
    unsigned short* h1       = (unsigned short*)(ws + 12800000);
    unsigned short* h2       = (unsigned short*)(ws + 25600000);
    unsigned short* aggb     = (unsigned short*)(ws + 38400000);
    unsigned short* wb       = (unsigned short*)(ws + 51200000);
    int*            s32      = (int*)(ws + 51462144);
    int*            d32      = (int*)(ws + 54662144);
    int*            deg      = (int*)(ws + 57862144);
    int*            rowstart = (int*)(ws + 58062208);
    int*            cursor   = (int*)(ws + 58262272);
    int*            nbr      = (int*)(ws + 58462336);
    float*          outp     = (float*)d_out;

    const unsigned short* w1l_b = wb;
    const unsigned short* w1r_b = wb + 16384;
    const unsigned short* w2l_b = wb + 32768;
    const unsigned short* w2r_b = wb + 49152;
    unsigned short*       wm1f  = wb + 65536;        // 65536 elems, fragment-ordered

    // prep: casts + fragment reorder + indices + CSR build
    cast_x_kernel<<<6250, 256, 0, stream>>>(x, xb);
    cast_w_kernel<<<64, 256, 0, stream>>>(W1l, W1r, W2l, W2r, wb);
    frag_wm1_kernel<<<32, 256, 0, stream>>>(Wm1, wm1f);
    edge_cvt_kernel<<<3125, 256, 0, stream>>>(ei, s32, d32);
    hipMemsetAsync(deg, 0, 200064, stream);
    hist_kernel<<<3125, 256, 0, stream>>>(d32, deg);
    scan_kernel<<<1, 1024, 0, stream>>>(deg, rowstart, cursor);
    fill_kernel<<<3125, 256, 0, stream>>>(s32, d32, cursor, nbr);

    // layer 1
    agg_gather_kernel<<<12500, 256, 0, stream>>>(xb, nbr, rowstart, aggb);
    node_gemm_kernel<<<782, 256, 0, stream>>>(aggb, xb, w1l_b, w1r_b, b1l, h1);
    // layer 2
    agg_gather_kernel<<<12500, 256, 0, stream>>>(h1, nbr, rowstart, aggb);
    node_gemm_kernel<<<782, 256, 0, stream>>>(aggb, h1, w2l_b, w2r_b, b2l, h2);
    // edge MLP
    edge_mlp_kernel<<<3125, 256, 0, stream>>>(h2, s32, d32, wm1f, bm1, Wm2, bm2, outp);
}